// Round 11
// baseline (109.715 us; speedup 1.0000x reference)
//
#include <hip/hip_runtime.h>
#include <hip/hip_bf16.h>

// SAGAN attention B=8, C=64, N=4096, Cr=8.
// prep: x -> (LDS transpose) -> W GEMM -> Qp, Kp, Vf (pi-permuted fragment-linear)
// attn: SOFTWARE-PIPELINED j-loop: iteration jt does PV(jt) with pk from last
//       iter, then QK+exp(jt+1) (K from LDS, no barrier dep) -> MFMA pipe (PV)
//       and VALU pipe (next tile's exp) overlap within each wave. 32 q/wave,
//       4-wave blocks, js x8, grid 2048 (deep queue). V dbuf + K slice = 24KB.
//       Natural register alloc (NO min-waves bound — r7 spill lesson).
//       Schraudolph exp2 + v_perm pack. Flat grid, b = bid&7 XCD pin.
// combine: sum 8 partials, normalize, gamma*o + x.
//
// ws layout (bytes):
//   [0    , 0.5M)  Qp [b][n][8] bf16 (Wf.x * log2e)
//   [0.5M , 1M  )  Kp [b][n][8] bf16
//   [1M   , 5M  )  Vf [b][jt64][kstep4][chalf2][lane64][e8] bf16 (8KB/slab, pi order)
//   [5M   , 6M  )  Lpart [js8][b][n] fp32
//   [6M   , 40M )  Opart [js8][b][n][c] bf16

#define N_ 4096
#define LOG2E 1.4426950408889634f

typedef __attribute__((ext_vector_type(8)))  __bf16 bf16x8;
typedef __attribute__((ext_vector_type(2)))  float  f32x2;
typedef __attribute__((ext_vector_type(4)))  float  f32x4;
typedef __attribute__((ext_vector_type(16))) float  f32x16;

union U16B { uint4 u; bf16x8 b; };

static __device__ inline uint pack_bf2(float a, float b) {
  __hip_bfloat162 h = __float22bfloat162_rn(make_float2(a, b));
  uint r; __builtin_memcpy(&r, &h, 4); return r;
}
static __device__ inline ushort f2bf(float a) {
  __hip_bfloat16 h = __float2bfloat16(a);
  ushort r; __builtin_memcpy(&r, &h, 2); return r;
}
static __device__ inline float bflo(uint u) {
  uint v = u << 16; float f; __builtin_memcpy(&f, &v, 4); return f;
}
static __device__ inline float bfhi(uint u) {
  uint v = u & 0xffff0000u; float f; __builtin_memcpy(&f, &v, 4); return f;
}
// Schraudolph 2^s: linear-mantissa approx in the int domain.
// 1 v_fma + 1 v_cvt (full rate) vs quarter-rate v_exp_f32. ~3% max err,
// largely cancelled by softmax normalization; finite for |s| < 120.
static __device__ inline uint fexp2i(float s) {
  return (uint)(int)(s * 8388608.0f + 1065353216.0f);
}
static __device__ inline float asf(uint u) {
  float f; __builtin_memcpy(&f, &u, 4); return f;
}

// ---------------- pass 1: fused transpose + projection ----------------
// flat grid 512: b = bid&7 (XCD pin), tile = bid>>3.
__global__ __launch_bounds__(256) void prep_kernel(
    const float* __restrict__ x,  const float* __restrict__ Wf,
    const float* __restrict__ Wg, const float* __restrict__ Wh,
    ushort* __restrict__ Qp, ushort* __restrict__ Kp, ushort* __restrict__ Vf)
{
  __shared__ __align__(16) char smem[37376];
  float*  T   = (float*)smem;              // 64x65 fp32 x-tile (reused as Vt 8KB)
  ushort* xTl = (ushort*)(smem + 16640);   // 64n x 72c bf16
  ushort* Wb  = (ushort*)(smem + 25856);   // 80 x 72 bf16
  const int bid = blockIdx.x;
  const int b = bid & 7, tile = bid >> 3, n0 = tile * 64;
  const int tid = threadIdx.x;

  { // stage x tile (coalesced by n)
    const int nl = tid & 63, cw = tid >> 6;
#pragma unroll
    for (int i = 0; i < 16; ++i) {
      const int c = i * 4 + cw;
      T[c * 65 + nl] = x[((size_t)(b * 64 + c)) * N_ + n0 + nl];
    }
  }
  { // stage weights
#pragma unroll
    for (int i = 0; i < 20; ++i) {
      const int e = i * 256 + tid;
      const int row = e >> 6, col = e & 63;
      float v;
      if (row < 8)       v = Wf[row * 64 + col] * LOG2E;
      else if (row < 16) v = Wg[(row - 8) * 64 + col];
      else               v = Wh[(row - 16) * 64 + col];
      Wb[row * 72 + col] = f2bf(v);
    }
  }
  __syncthreads();
  { // transpose to xTl [n][c] bf16
    const int n = tid >> 2, cq = (tid & 3) * 16;
    uint o[8];
#pragma unroll
    for (int j = 0; j < 8; ++j)
      o[j] = pack_bf2(T[(cq + 2 * j) * 65 + n], T[(cq + 2 * j + 1) * 65 + n]);
    *(uint4*)(xTl + n * 72 + cq)     = make_uint4(o[0], o[1], o[2], o[3]);
    *(uint4*)(xTl + n * 72 + cq + 8) = make_uint4(o[4], o[5], o[6], o[7]);
  }
  __syncthreads();

  const int l = tid & 63, w = tid >> 6, l15 = l & 15, lq = l >> 4;
  const int nn = w * 16 + l15;
  U16B bf0, bf1;
  bf0.u = *(const uint4*)(xTl + nn * 72 + lq * 8);
  bf1.u = *(const uint4*)(xTl + nn * 72 + 32 + lq * 8);
  f32x4 acc[5];
#pragma unroll
  for (int mt = 0; mt < 5; ++mt) {
    U16B a0, a1;
    a0.u = *(const uint4*)(Wb + (mt * 16 + l15) * 72 + lq * 8);
    a1.u = *(const uint4*)(Wb + (mt * 16 + l15) * 72 + 32 + lq * 8);
    f32x4 c0 = __builtin_amdgcn_mfma_f32_16x16x32_bf16(a0.b, bf0.b, (f32x4){0.f,0.f,0.f,0.f}, 0, 0, 0);
    acc[mt]  = __builtin_amdgcn_mfma_f32_16x16x32_bf16(a1.b, bf1.b, c0, 0, 0, 0);
  }
  const int n = n0 + nn;
  { // rows 0-7 -> Q, 8-15 -> K  (C: col=n=l15, row=lq*4+r)
    uint lo = pack_bf2(acc[0][0], acc[0][1]);
    uint hi = pack_bf2(acc[0][2], acc[0][3]);
    ushort* dst = (lq < 2 ? Qp : Kp) + ((size_t)(b * N_ + n)) * 8 + (lq & 1) * 4;
    *(uint2*)dst = make_uint2(lo, hi);
  }
  // V -> pi-permuted fragment-linear LDS slab (overwrites T; T dead)
  ushort* Vt = (ushort*)smem;
  const int jp = nn;                       // j within tile, 0..63
  const int jl = jp & 31, stp = (jl >> 4) & 1, j16 = jl & 15;
  const int s  = (j16 & 3) | ((j16 & 4) << 1) | ((j16 & 8) >> 1);  // inverse-pi slot
  const int vbase = ((jp >> 5) * 2 + stp) * 1024 + (s >> 3) * 256 + (s & 7);
#pragma unroll
  for (int mt = 1; mt < 5; ++mt)
#pragma unroll
    for (int r = 0; r < 4; ++r) {
      const int c = (mt - 1) * 16 + lq * 4 + r;
      Vt[vbase + (c >> 5) * 512 + (c & 31) * 8] = f2bf(acc[mt][r]);
    }
  __syncthreads();
  const uint4* src = (const uint4*)Vt;
  uint4* dst = (uint4*)(Vf + ((size_t)(b * 64 + tile)) * 4096);
  dst[tid]       = src[tid];
  dst[256 + tid] = src[256 + tid];
}

// ---------------- pass 2: pipelined flash attention ----------------
// flat grid 2048 blocks x 256 thr (4 waves). b = bid&7 (XCD pin),
// js = (bid>>3)&7, qblk = bid>>6 (0..31). 128 q/block, 32 q/wave,
// 8 j-tiles of 64 per block. LDS: V dbuf 16KB + K slice 8KB = 24KB.
__global__ __launch_bounds__(256) void attn_kernel(
    const ushort* __restrict__ Qp, const ushort* __restrict__ Kp,
    const ushort* __restrict__ Vf,
    ushort* __restrict__ Opart, float* __restrict__ Lpart)
{
  __shared__ __align__(16) uint4 smem4[1536];   // [0,1024) V dbuf | [1024,1536) K
  uint4* vsl = smem4;
  uint4* Kl  = smem4 + 1024;
  const int bid = blockIdx.x;
  const int b = bid & 7, js = (bid >> 3) & 7, qblk = bid >> 6;
  const int tid = threadIdx.x, w = tid >> 6, l = tid & 63;
  const int l31 = l & 31, lq1 = l >> 5;
  const int q0w = qblk * 128 + w * 32;
  const int jb0 = js * 512;
  const uint4 zero4 = make_uint4(0u, 0u, 0u, 0u);

  // stage K slice (512 rows x 16B) + first V slab
  const uint4* Kg = (const uint4*)(Kp + ((size_t)(b * N_ + jb0)) * 8);
  Kl[tid]       = Kg[tid];
  Kl[256 + tid] = Kg[256 + tid];
  const uint4* Vg = (const uint4*)(Vf + ((size_t)(b * 64 + js * 8)) * 4096);
  vsl[tid]       = Vg[tid];
  vsl[256 + tid] = Vg[256 + tid];

  // Q B-frag: lanes 0-31 real (k=d 0..7), lanes 32-63 ZERO (kills A garbage at k>=8)
  U16B qf;
  qf.u = lq1 ? zero4 : *(const uint4*)(Qp + ((size_t)(b * N_ + q0w + l31)) * 8);

  const f32x16 Oz = {0,0,0,0,0,0,0,0,0,0,0,0,0,0,0,0};
  f32x16 O[2] = {Oz, Oz};                  // [chalf], 32 AGPR total
  f32x2 Lv = {0.f, 0.f};
  uint pk[2][8], pkn[2][8];                // [jc][dword], cur + next
  uint4 vp0, vp1;
  int p = 0;
  __syncthreads();                         // K + slab 0 visible

  // --- prologue: QK+exp for tile 0 -> pk ---
#pragma unroll
  for (int jc = 0; jc < 2; ++jc) {
    U16B kf; kf.u = Kl[jc * 32 + l31];
    f32x16 St = __builtin_amdgcn_mfma_f32_32x32x16_bf16(kf.b, qf.b, Oz, 0, 0, 0);
    uint ib[16];
#pragma unroll
    for (int r = 0; r < 16; ++r) ib[r] = fexp2i(St[r]);
    f32x2 t0 = {asf(ib[0]), asf(ib[1])},  t1 = {asf(ib[2]),  asf(ib[3])};
    f32x2 t2 = {asf(ib[4]), asf(ib[5])},  t3 = {asf(ib[6]),  asf(ib[7])};
    f32x2 t4 = {asf(ib[8]), asf(ib[9])},  t5 = {asf(ib[10]), asf(ib[11])};
    f32x2 t6 = {asf(ib[12]), asf(ib[13])}, t7 = {asf(ib[14]), asf(ib[15])};
    Lv += ((t0 + t1) + (t2 + t3)) + ((t4 + t5) + (t6 + t7));
#pragma unroll
    for (int d = 0; d < 8; ++d)
      pk[jc][d] = __builtin_amdgcn_perm(ib[2 * d + 1], ib[2 * d], 0x07060302u);
  }

#pragma unroll
  for (int jt = 0; jt < 8; ++jt) {
    if (jt < 7) {  // register prefetch of next V slab (vmcnt spans whole body)
      vp0 = Vg[(jt + 1) * 512 + tid];
      vp1 = Vg[(jt + 1) * 512 + 256 + tid];
    }
    // --- PV(tile jt): MFMA pipe.  pi-permuted j handled by Vf layout. ---
    const uint4* vb = vsl + p * 512;
#pragma unroll
    for (int jc = 0; jc < 2; ++jc)
#pragma unroll
      for (int h = 0; h < 2; ++h) {
        U16B pa;
        pa.u = make_uint4(pk[jc][h * 4], pk[jc][h * 4 + 1],
                          pk[jc][h * 4 + 2], pk[jc][h * 4 + 3]);
        const int ks = jc * 2 + h;
#pragma unroll
        for (int ch = 0; ch < 2; ++ch) {
          U16B vfr; vfr.u = vb[ks * 128 + ch * 64 + l];
          O[ch] = __builtin_amdgcn_mfma_f32_32x32x16_bf16(pa.b, vfr.b, O[ch], 0, 0, 0);
        }
      }
    // --- QK+exp(tile jt+1): VALU pipe, independent of PV above (overlaps) ---
    if (jt < 7) {
#pragma unroll
      for (int jc = 0; jc < 2; ++jc) {
        U16B kf; kf.u = Kl[(jt + 1) * 64 + jc * 32 + l31];
        f32x16 St = __builtin_amdgcn_mfma_f32_32x32x16_bf16(kf.b, qf.b, Oz, 0, 0, 0);
        uint ib[16];
#pragma unroll
        for (int r = 0; r < 16; ++r) ib[r] = fexp2i(St[r]);
        f32x2 t0 = {asf(ib[0]), asf(ib[1])},  t1 = {asf(ib[2]),  asf(ib[3])};
        f32x2 t2 = {asf(ib[4]), asf(ib[5])},  t3 = {asf(ib[6]),  asf(ib[7])};
        f32x2 t4 = {asf(ib[8]), asf(ib[9])},  t5 = {asf(ib[10]), asf(ib[11])};
        f32x2 t6 = {asf(ib[12]), asf(ib[13])}, t7 = {asf(ib[14]), asf(ib[15])};
        Lv += ((t0 + t1) + (t2 + t3)) + ((t4 + t5) + (t6 + t7));
#pragma unroll
        for (int d = 0; d < 8; ++d)
          pkn[jc][d] = __builtin_amdgcn_perm(ib[2 * d + 1], ib[2 * d], 0x07060302u);
      }
      // stage prefetched slab into the other buffer (WAR guarded by barrier)
      vsl[(p ^ 1) * 512 + tid]       = vp0;
      vsl[(p ^ 1) * 512 + 256 + tid] = vp1;
#pragma unroll
      for (int jc = 0; jc < 2; ++jc)
#pragma unroll
        for (int d = 0; d < 8; ++d) pk[jc][d] = pkn[jc][d];
    }
    __syncthreads();
    p ^= 1;
  }

  // partial denominator: lanes l and l+32 hold disjoint j for the same q=l31
  float L = Lv.x + Lv.y;
  L += __shfl_xor(L, 32);
  if (lq1 == 0)
    Lpart[((size_t)(js * 8 + b)) * N_ + q0w + l31] = L;

  // partial O: row q = (r&3)+8*(r>>2)+4*lq1, col c = ch*32 + l31
  ushort* Op = Opart + (((size_t)(js * 8 + b)) * N_ + q0w) * 64;
#pragma unroll
  for (int ch = 0; ch < 2; ++ch)
#pragma unroll
    for (int g = 0; g < 4; ++g)
#pragma unroll
      for (int r = 0; r < 4; ++r) {
        const int q = r + 8 * g + 4 * lq1;
        Op[q * 64 + ch * 32 + l31] = f2bf(O[ch][g * 4 + r]);
      }
}

// ---------------- pass 3: combine partials + normalize + gamma*o + x ----------------
// flat grid 512: b = bid&7 (XCD pin, matches attn's Opart locality).
__global__ __launch_bounds__(256) void combine_kernel(
    const ushort* __restrict__ Opart, const float* __restrict__ Lpart,
    const float* __restrict__ x, const float* __restrict__ gamma,
    float* __restrict__ out)
{
  __shared__ float T[64 * 65];
  const int bid = blockIdx.x;
  const int b = bid & 7, n0 = (bid >> 3) * 64;
  const int tid = threadIdx.x;
  float acc[16];
#pragma unroll
  for (int e = 0; e < 16; ++e) acc[e] = 0.f;
#pragma unroll
  for (int js = 0; js < 8; ++js) {
    const ushort* Op = Opart + (((size_t)(js * 8 + b)) * N_ + n0) * 64 + tid * 16;
    uint4 a  = *(const uint4*)Op;
    uint4 c2 = *(const uint4*)(Op + 8);
    acc[0] += bflo(a.x);  acc[1] += bfhi(a.x);  acc[2] += bflo(a.y);  acc[3] += bfhi(a.y);
    acc[4] += bflo(a.z);  acc[5] += bfhi(a.z);  acc[6] += bflo(a.w);  acc[7] += bfhi(a.w);
    acc[8] += bflo(c2.x); acc[9] += bfhi(c2.x); acc[10]+= bflo(c2.y); acc[11]+= bfhi(c2.y);
    acc[12]+= bflo(c2.z); acc[13]+= bfhi(c2.z); acc[14]+= bflo(c2.w); acc[15]+= bfhi(c2.w);
  }
  const int nr = tid >> 2, c0 = (tid & 3) * 16;
#pragma unroll
  for (int e = 0; e < 16; ++e) T[nr * 65 + c0 + e] = acc[e];
  __syncthreads();
  const float g = gamma[0];
  const int n = tid & 63, cq = (tid >> 6) * 16;
  float Ls = 0.f;
#pragma unroll
  for (int js = 0; js < 8; ++js) Ls += Lpart[((size_t)(js * 8 + b)) * N_ + n0 + n];
  const float gr = g / Ls;
#pragma unroll
  for (int i = 0; i < 16; ++i) {
    const int c = cq + i;
    const size_t oi = ((size_t)(b * 64 + c)) * N_ + n0 + n;
    out[oi] = gr * T[n * 65 + c] + x[oi];
  }
}

extern "C" void kernel_launch(void* const* d_in, const int* in_sizes, int n_in,
                              void* d_out, int out_size, void* d_ws, size_t ws_size,
                              hipStream_t stream) {
  const float* x     = (const float*)d_in[0];
  const float* Wf    = (const float*)d_in[1];
  const float* Wg    = (const float*)d_in[2];
  const float* Wh    = (const float*)d_in[3];
  const float* gamma = (const float*)d_in[4];
  float* out = (float*)d_out;
  char* ws = (char*)d_ws;

  ushort* Qp    = (ushort*)(ws);
  ushort* Kp    = (ushort*)(ws + 512 * 1024);
  ushort* Vf    = (ushort*)(ws + 1024 * 1024);       // 4 MB
  float*  Lpart = (float*) (ws + 5 * 1024 * 1024);   // 1 MB
  ushort* Opart = (ushort*)(ws + 6 * 1024 * 1024);   // 33.5 MB

  prep_kernel   <<<512,  256, 0, stream>>>(x, Wf, Wg, Wh, Qp, Kp, Vf);
  attn_kernel   <<<2048, 256, 0, stream>>>(Qp, Kp, Vf, Opart, Lpart);
  combine_kernel<<<512,  256, 0, stream>>>(Opart, Lpart, x, gamma, out);
}

// Round 12
// 105.752 us; speedup vs baseline: 1.0375x; 1.0375x over previous
//
#include <hip/hip_runtime.h>
#include <hip/hip_bf16.h>

// SAGAN attention B=8, C=64, N=4096, Cr=8.
// prep: x -> (LDS transpose) -> W GEMM -> Qp, Kp, Vf (pi-permuted fragment-linear)
// attn: r10 shell (512-thr blocks, 32 q/wave, js x4, (512,4) bound, K in LDS,
//       V LDS double-buffer) + RAW-BARRIER PIPELINE: s_waitcnt lgkmcnt(0) +
//       s_barrier via inline asm (NO vmcnt(0) drain -> global V prefetch stays
//       in flight across barriers), 2-tile prefetch distance (vp2 issued at jt
//       for tile jt+2, staged at jt+1). Schraudolph exp2 + v_perm pack.
//       Flat grid, b = bid&7 XCD pin.
// combine: sum 4 partials, normalize, gamma*o + x.
//
// ws layout (bytes):
//   [0    , 0.5M)  Qp [b][n][8] bf16 (Wf.x * log2e)
//   [0.5M , 1M  )  Kp [b][n][8] bf16
//   [1M   , 5M  )  Vf [b][jt64][kstep4][chalf2][lane64][e8] bf16 (8KB/slab, pi order)
//   [5M   , 5.5M)  Lpart [js4][b][n] fp32
//   [6M   , 23M )  Opart [js4][b][n][c] bf16

#define N_ 4096
#define LOG2E 1.4426950408889634f

typedef __attribute__((ext_vector_type(8)))  __bf16 bf16x8;
typedef __attribute__((ext_vector_type(2)))  float  f32x2;
typedef __attribute__((ext_vector_type(4)))  float  f32x4;
typedef __attribute__((ext_vector_type(16))) float  f32x16;

union U16B { uint4 u; bf16x8 b; };

static __device__ inline uint pack_bf2(float a, float b) {
  __hip_bfloat162 h = __float22bfloat162_rn(make_float2(a, b));
  uint r; __builtin_memcpy(&r, &h, 4); return r;
}
static __device__ inline ushort f2bf(float a) {
  __hip_bfloat16 h = __float2bfloat16(a);
  ushort r; __builtin_memcpy(&r, &h, 2); return r;
}
static __device__ inline float bflo(uint u) {
  uint v = u << 16; float f; __builtin_memcpy(&f, &v, 4); return f;
}
static __device__ inline float bfhi(uint u) {
  uint v = u & 0xffff0000u; float f; __builtin_memcpy(&f, &v, 4); return f;
}
// Schraudolph 2^s (int-domain linear-mantissa): 1 v_fma + 1 v_cvt, full rate.
// ~3% max err, mostly cancelled by softmax normalization; finite for |s| < 120.
static __device__ inline uint fexp2i(float s) {
  return (uint)(int)(s * 8388608.0f + 1065353216.0f);
}
static __device__ inline float asf(uint u) {
  float f; __builtin_memcpy(&f, &u, 4); return f;
}
// Workgroup barrier WITHOUT the compiler's vmcnt(0) drain: only LDS ops are
// waited (lgkmcnt), so in-flight global prefetch loads (private regs) cross
// the barrier. This is the structural fix for the __syncthreads drain stall.
static __device__ inline void lds_barrier() {
  asm volatile("s_waitcnt lgkmcnt(0)\n\ts_barrier" ::: "memory");
}

// ---------------- pass 1: fused transpose + projection ----------------
// flat grid 512: b = bid&7 (XCD pin), tile = bid>>3.
__global__ __launch_bounds__(256) void prep_kernel(
    const float* __restrict__ x,  const float* __restrict__ Wf,
    const float* __restrict__ Wg, const float* __restrict__ Wh,
    ushort* __restrict__ Qp, ushort* __restrict__ Kp, ushort* __restrict__ Vf)
{
  __shared__ __align__(16) char smem[37376];
  float*  T   = (float*)smem;              // 64x65 fp32 x-tile (reused as Vt 8KB)
  ushort* xTl = (ushort*)(smem + 16640);   // 64n x 72c bf16
  ushort* Wb  = (ushort*)(smem + 25856);   // 80 x 72 bf16
  const int bid = blockIdx.x;
  const int b = bid & 7, tile = bid >> 3, n0 = tile * 64;
  const int tid = threadIdx.x;

  { // stage x tile (coalesced by n)
    const int nl = tid & 63, cw = tid >> 6;
#pragma unroll
    for (int i = 0; i < 16; ++i) {
      const int c = i * 4 + cw;
      T[c * 65 + nl] = x[((size_t)(b * 64 + c)) * N_ + n0 + nl];
    }
  }
  { // stage weights
#pragma unroll
    for (int i = 0; i < 20; ++i) {
      const int e = i * 256 + tid;
      const int row = e >> 6, col = e & 63;
      float v;
      if (row < 8)       v = Wf[row * 64 + col] * LOG2E;
      else if (row < 16) v = Wg[(row - 8) * 64 + col];
      else               v = Wh[(row - 16) * 64 + col];
      Wb[row * 72 + col] = f2bf(v);
    }
  }
  __syncthreads();
  { // transpose to xTl [n][c] bf16
    const int n = tid >> 2, cq = (tid & 3) * 16;
    uint o[8];
#pragma unroll
    for (int j = 0; j < 8; ++j)
      o[j] = pack_bf2(T[(cq + 2 * j) * 65 + n], T[(cq + 2 * j + 1) * 65 + n]);
    *(uint4*)(xTl + n * 72 + cq)     = make_uint4(o[0], o[1], o[2], o[3]);
    *(uint4*)(xTl + n * 72 + cq + 8) = make_uint4(o[4], o[5], o[6], o[7]);
  }
  __syncthreads();

  const int l = tid & 63, w = tid >> 6, l15 = l & 15, lq = l >> 4;
  const int nn = w * 16 + l15;
  U16B bf0, bf1;
  bf0.u = *(const uint4*)(xTl + nn * 72 + lq * 8);
  bf1.u = *(const uint4*)(xTl + nn * 72 + 32 + lq * 8);
  f32x4 acc[5];
#pragma unroll
  for (int mt = 0; mt < 5; ++mt) {
    U16B a0, a1;
    a0.u = *(const uint4*)(Wb + (mt * 16 + l15) * 72 + lq * 8);
    a1.u = *(const uint4*)(Wb + (mt * 16 + l15) * 72 + 32 + lq * 8);
    f32x4 c0 = __builtin_amdgcn_mfma_f32_16x16x32_bf16(a0.b, bf0.b, (f32x4){0.f,0.f,0.f,0.f}, 0, 0, 0);
    acc[mt]  = __builtin_amdgcn_mfma_f32_16x16x32_bf16(a1.b, bf1.b, c0, 0, 0, 0);
  }
  const int n = n0 + nn;
  { // rows 0-7 -> Q, 8-15 -> K  (C: col=n=l15, row=lq*4+r)
    uint lo = pack_bf2(acc[0][0], acc[0][1]);
    uint hi = pack_bf2(acc[0][2], acc[0][3]);
    ushort* dst = (lq < 2 ? Qp : Kp) + ((size_t)(b * N_ + n)) * 8 + (lq & 1) * 4;
    *(uint2*)dst = make_uint2(lo, hi);
  }
  // V -> pi-permuted fragment-linear LDS slab (overwrites T; T dead)
  ushort* Vt = (ushort*)smem;
  const int jp = nn;                       // j within tile, 0..63
  const int jl = jp & 31, stp = (jl >> 4) & 1, j16 = jl & 15;
  const int s  = (j16 & 3) | ((j16 & 4) << 1) | ((j16 & 8) >> 1);  // inverse-pi slot
  const int vbase = ((jp >> 5) * 2 + stp) * 1024 + (s >> 3) * 256 + (s & 7);
#pragma unroll
  for (int mt = 1; mt < 5; ++mt)
#pragma unroll
    for (int r = 0; r < 4; ++r) {
      const int c = (mt - 1) * 16 + lq * 4 + r;
      Vt[vbase + (c >> 5) * 512 + (c & 31) * 8] = f2bf(acc[mt][r]);
    }
  __syncthreads();
  const uint4* src = (const uint4*)Vt;
  uint4* dst = (uint4*)(Vf + ((size_t)(b * 64 + tile)) * 4096);
  dst[tid]       = src[tid];
  dst[256 + tid] = src[256 + tid];
}

// ---------------- pass 2: raw-barrier pipelined flash attention ----------------
// flat grid 512 blocks x 512 thr (8 waves). b = bid&7 (XCD pin), js = (bid>>3)&3,
// qblk = bid>>5 (16). 256 q/block, 32 q/wave, 16 j-tiles of 64 per block.
// LDS: V dbuf 16KB + K slice 16KB = 32KB.
__global__ __launch_bounds__(512, 4) void attn_kernel(
    const ushort* __restrict__ Qp, const ushort* __restrict__ Kp,
    const ushort* __restrict__ Vf,
    ushort* __restrict__ Opart, float* __restrict__ Lpart)
{
  __shared__ __align__(16) uint4 smem4[2048];   // [0,1024) V dbuf | [1024,2048) K
  uint4* vsl = smem4;
  uint4* Kl  = smem4 + 1024;
  const int bid = blockIdx.x;
  const int b = bid & 7, js = (bid >> 3) & 3, qblk = bid >> 5;
  const int tid = threadIdx.x, w = tid >> 6, l = tid & 63;
  const int l31 = l & 31, lq1 = l >> 5;
  const int q0w = qblk * 256 + w * 32;
  const int jb0 = js * 1024;
  const uint4 zero4 = make_uint4(0u, 0u, 0u, 0u);

  // stage K slice (1024 rows x 16B, 2 uint4/thread) + first V slab (1/thread)
  const uint4* Kg = (const uint4*)(Kp + ((size_t)(b * N_ + jb0)) * 8);
  Kl[tid]       = Kg[tid];
  Kl[512 + tid] = Kg[512 + tid];
  const uint4* Vg = (const uint4*)(Vf + ((size_t)(b * 64 + js * 16)) * 4096);
  vsl[tid] = Vg[tid];
  uint4 vp1 = Vg[512 + tid];               // tile 1, in flight across barrier

  // Q B-frag: lanes 0-31 real (k=d 0..7), lanes 32-63 ZERO (kills A garbage at k>=8)
  U16B qf;
  qf.u = lq1 ? zero4 : *(const uint4*)(Qp + ((size_t)(b * N_ + q0w + l31)) * 8);

  const f32x16 Oz = {0,0,0,0,0,0,0,0,0,0,0,0,0,0,0,0};
  f32x16 O[2] = {Oz, Oz};                  // [chalf], 32 AGPR total
  f32x2 Lv = {0.f, 0.f};
  uint pk[2][8];                           // [jc][dword]
  lds_barrier();                           // K + slab 0 visible; vp1 stays in flight

  // prologue: QK+exp(tile 0) -> pk
#pragma unroll
  for (int jc = 0; jc < 2; ++jc) {
    U16B kf; kf.u = Kl[jc * 32 + l31];
    f32x16 St = __builtin_amdgcn_mfma_f32_32x32x16_bf16(kf.b, qf.b, Oz, 0, 0, 0);
    uint ib[16];
#pragma unroll
    for (int r = 0; r < 16; ++r) ib[r] = fexp2i(St[r]);
    f32x2 t0 = {asf(ib[0]), asf(ib[1])},  t1 = {asf(ib[2]),  asf(ib[3])};
    f32x2 t2 = {asf(ib[4]), asf(ib[5])},  t3 = {asf(ib[6]),  asf(ib[7])};
    f32x2 t4 = {asf(ib[8]), asf(ib[9])},  t5 = {asf(ib[10]), asf(ib[11])};
    f32x2 t6 = {asf(ib[12]), asf(ib[13])}, t7 = {asf(ib[14]), asf(ib[15])};
    Lv += ((t0 + t1) + (t2 + t3)) + ((t4 + t5) + (t6 + t7));
#pragma unroll
    for (int d = 0; d < 8; ++d)
      pk[jc][d] = __builtin_amdgcn_perm(ib[2 * d + 1], ib[2 * d], 0x07060302u);
  }

  int p = 0;
  for (int jt = 0; jt < 16; ++jt) {
    uint4 vp2 = zero4;
    if (jt < 14) vp2 = Vg[(jt + 2) * 512 + tid];  // 2-tile distance, never drained
    // --- PV(jt): consumes pk; pi-permuted j handled by Vf layout ---
    const uint4* vb = vsl + p * 512;
#pragma unroll
    for (int jc = 0; jc < 2; ++jc)
#pragma unroll
      for (int h = 0; h < 2; ++h) {
        U16B pa;
        pa.u = make_uint4(pk[jc][h * 4], pk[jc][h * 4 + 1],
                          pk[jc][h * 4 + 2], pk[jc][h * 4 + 3]);
        const int ks = jc * 2 + h;
#pragma unroll
        for (int ch = 0; ch < 2; ++ch) {
          U16B vfr; vfr.u = vb[ks * 128 + ch * 64 + l];
          O[ch] = __builtin_amdgcn_mfma_f32_32x32x16_bf16(pa.b, vfr.b, O[ch], 0, 0, 0);
        }
      }
    // --- QK+exp(jt+1) -> pk in place (pk dead after PV above) ---
    if (jt < 15) {
#pragma unroll
      for (int jc = 0; jc < 2; ++jc) {
        U16B kf; kf.u = Kl[(jt + 1) * 64 + jc * 32 + l31];
        f32x16 St = __builtin_amdgcn_mfma_f32_32x32x16_bf16(kf.b, qf.b, Oz, 0, 0, 0);
        uint ib[16];
#pragma unroll
        for (int r = 0; r < 16; ++r) ib[r] = fexp2i(St[r]);
        f32x2 t0 = {asf(ib[0]), asf(ib[1])},  t1 = {asf(ib[2]),  asf(ib[3])};
        f32x2 t2 = {asf(ib[4]), asf(ib[5])},  t3 = {asf(ib[6]),  asf(ib[7])};
        f32x2 t4 = {asf(ib[8]), asf(ib[9])},  t5 = {asf(ib[10]), asf(ib[11])};
        f32x2 t6 = {asf(ib[12]), asf(ib[13])}, t7 = {asf(ib[14]), asf(ib[15])};
        Lv += ((t0 + t1) + (t2 + t3)) + ((t4 + t5) + (t6 + t7));
#pragma unroll
        for (int d = 0; d < 8; ++d)
          pk[jc][d] = __builtin_amdgcn_perm(ib[2 * d + 1], ib[2 * d], 0x07060302u);
      }
      // stage tile jt+1 (vp1 issued >= 1 body + barrier ago; only waits its own vmcnt)
      vsl[(p ^ 1) * 512 + tid] = vp1;
    }
    lds_barrier();                         // LDS-only wait; vp2 stays in flight
    p ^= 1;
    vp1 = vp2;
  }

  // partial denominator: lanes l and l+32 hold disjoint j for the same q=l31
  float L = Lv.x + Lv.y;
  L += __shfl_xor(L, 32);
  if (lq1 == 0)
    Lpart[((size_t)(js * 8 + b)) * N_ + q0w + l31] = L;

  // partial O: row q = (r&3)+8*(r>>2)+4*lq1, col c = ch*32 + l31
  ushort* Op = Opart + (((size_t)(js * 8 + b)) * N_ + q0w) * 64;
#pragma unroll
  for (int ch = 0; ch < 2; ++ch)
#pragma unroll
    for (int g = 0; g < 4; ++g)
#pragma unroll
      for (int r = 0; r < 4; ++r) {
        const int q = r + 8 * g + 4 * lq1;
        Op[q * 64 + ch * 32 + l31] = f2bf(O[ch][g * 4 + r]);
      }
}

// ---------------- pass 3: combine partials + normalize + gamma*o + x ----------------
// flat grid 512: b = bid&7 (XCD pin, matches attn's Opart locality).
__global__ __launch_bounds__(256) void combine_kernel(
    const ushort* __restrict__ Opart, const float* __restrict__ Lpart,
    const float* __restrict__ x, const float* __restrict__ gamma,
    float* __restrict__ out)
{
  __shared__ float T[64 * 65];
  const int bid = blockIdx.x;
  const int b = bid & 7, n0 = (bid >> 3) * 64;
  const int tid = threadIdx.x;
  float acc[16];
#pragma unroll
  for (int e = 0; e < 16; ++e) acc[e] = 0.f;
#pragma unroll
  for (int js = 0; js < 4; ++js) {
    const ushort* Op = Opart + (((size_t)(js * 8 + b)) * N_ + n0) * 64 + tid * 16;
    uint4 a  = *(const uint4*)Op;
    uint4 c2 = *(const uint4*)(Op + 8);
    acc[0] += bflo(a.x);  acc[1] += bfhi(a.x);  acc[2] += bflo(a.y);  acc[3] += bfhi(a.y);
    acc[4] += bflo(a.z);  acc[5] += bfhi(a.z);  acc[6] += bflo(a.w);  acc[7] += bfhi(a.w);
    acc[8] += bflo(c2.x); acc[9] += bfhi(c2.x); acc[10]+= bflo(c2.y); acc[11]+= bfhi(c2.y);
    acc[12]+= bflo(c2.z); acc[13]+= bfhi(c2.z); acc[14]+= bflo(c2.w); acc[15]+= bfhi(c2.w);
  }
  const int nr = tid >> 2, c0 = (tid & 3) * 16;
#pragma unroll
  for (int e = 0; e < 16; ++e) T[nr * 65 + c0 + e] = acc[e];
  __syncthreads();
  const float g = gamma[0];
  const int n = tid & 63, cq = (tid >> 6) * 16;
  float Ls = 0.f;
#pragma unroll
  for (int js = 0; js < 4; ++js) Ls += Lpart[((size_t)(js * 8 + b)) * N_ + n0 + n];
  const float gr = g / Ls;
#pragma unroll
  for (int i = 0; i < 16; ++i) {
    const int c = cq + i;
    const size_t oi = ((size_t)(b * 64 + c)) * N_ + n0 + n;
    out[oi] = gr * T[n * 65 + c] + x[oi];
  }
}

extern "C" void kernel_launch(void* const* d_in, const int* in_sizes, int n_in,
                              void* d_out, int out_size, void* d_ws, size_t ws_size,
                              hipStream_t stream) {
  const float* x     = (const float*)d_in[0];
  const float* Wf    = (const float*)d_in[1];
  const float* Wg    = (const float*)d_in[2];
  const float* Wh    = (const float*)d_in[3];
  const float* gamma = (const float*)d_in[4];
  float* out = (float*)d_out;
  char* ws = (char*)d_ws;

  ushort* Qp    = (ushort*)(ws);
  ushort* Kp    = (ushort*)(ws + 512 * 1024);
  ushort* Vf    = (ushort*)(ws + 1024 * 1024);       // 4 MB
  float*  Lpart = (float*) (ws + 5 * 1024 * 1024);   // 512 KB
  ushort* Opart = (ushort*)(ws + 6 * 1024 * 1024);   // 16.75 MB

  prep_kernel   <<<512, 256, 0, stream>>>(x, Wf, Wg, Wh, Qp, Kp, Vf);
  attn_kernel   <<<512, 512, 0, stream>>>(Qp, Kp, Vf, Opart, Lpart);
  combine_kernel<<<512, 256, 0, stream>>>(Opart, Lpart, x, gamma, out);
}